// Round 8
// baseline (1096.129 us; speedup 1.0000x reference)
//
#include <hip/hip_runtime.h>
#include <hip/hip_bf16.h>
#include <stdint.h>

typedef uint16_t u16;
typedef uint32_t u32;
typedef uint64_t u64;
typedef short bf16x8 __attribute__((ext_vector_type(8)));   // 8 bf16 in 4 VGPRs
typedef float f32x2 __attribute__((ext_vector_type(2)));
typedef float f32x4 __attribute__((ext_vector_type(4)));
typedef u32 u32x4 __attribute__((ext_vector_type(4)));

#define E_N 131072
#define T_N 1048576

__device__ __forceinline__ float bf2f(u32 u) { return __builtin_bit_cast(float, u << 16); }
__device__ __forceinline__ u16 f2bf(float f) {
  u32 u = __builtin_bit_cast(u32, f);
  return (u16)((u + 0x7fffu + ((u >> 16) & 1u)) >> 16);   // RNE
}
__device__ __forceinline__ float silu_f(float x) { return x / (1.0f + __expf(-x)); }
__device__ __forceinline__ f32x4 mfma16(bf16x8 a, bf16x8 b, f32x4 c) {
  return __builtin_amdgcn_mfma_f32_16x16x32_bf16(a, b, c, 0, 0, 0);
}
__device__ __forceinline__ void gld_lds16(const void* g, void* l) {
  __builtin_amdgcn_global_load_lds((const __attribute__((address_space(1))) u32*)g,
                                   (__attribute__((address_space(3))) u32*)l, 16, 0, 0);
}
#define WAIT_VM0() do { asm volatile("s_waitcnt vmcnt(0)" ::: "memory"); \
                        __builtin_amdgcn_sched_barrier(0); } while (0)

// Fragment-major weight layout (16-tile x 4-kstep): frag is 1KB, lane*16B.
__device__ __forceinline__ bf16x8 ldfrag(const char* base, u32 tile, u32 ks, u32 lane) {
  return *(const bf16x8*)(base + (((tile << 2) + ks) << 10) + lane * 16);
}

// ---------------------------------------------------------------------------
// T0: convert all f32 weights into bf16 layouts.
//  region 0 (ws+0     ): W2F frag-major 16 tiles (n<128 Wji else Wkj)    32768
//  region 1 (ws+65536 ): WS  frag-major K=1024 stack: [8 nt][32 kc][64][8]
//                        value = W_stack[k][n], k=b*128+h (flat col b*128+h)
//  region 2 (ws+327680): rT  PLAIN [5][n=128][k=128]                     81920
__global__ __launch_bounds__(256) void k_transpose(
    const float* __restrict__ Wji, const float* __restrict__ Wkj, const float* __restrict__ Wbil,
    const float* __restrict__ w11, const float* __restrict__ w12,
    const float* __restrict__ w21, const float* __restrict__ w22, const float* __restrict__ wout,
    u16* __restrict__ dst) {
  u32 idx = blockIdx.x * 256 + threadIdx.x;
  if (idx >= 245760) return;
  float v;
  if (idx < 32768) {          // W2F
    u32 j = idx & 7, lane = (idx >> 3) & 63, ks = (idx >> 9) & 3, g = idx >> 11;
    u32 k = ((ks << 2) + (lane >> 4)) * 8 + j;
    u32 n = g * 16 + (lane & 15);
    v = (n < 128) ? Wji[k * 128 + n] : Wkj[k * 128 + (n - 128)];
  } else if (idx < 163840) {  // WS (K=1024 stack, frag-major)
    u32 q = idx - 32768;
    u32 j = q & 7, lane = (q >> 3) & 63, kc = (q >> 9) & 31, nt = q >> 14;
    u32 k = kc * 32 + ((lane >> 4) * 8) + j;      // 0..1023
    u32 n = nt * 16 + (lane & 15);
    u32 b = k >> 7, h = k & 127;
    v = Wbil[h * 1024 + b * 128 + n];
  } else {                    // rT plain [n][k]
    u32 q = idx - 163840;
    u32 r = q >> 14, n = (q >> 7) & 127, h = q & 127;
    const float* src = (r == 0) ? w11 : (r == 1) ? w12 : (r == 2) ? w21 : (r == 3) ? w22 : wout;
    v = src[h * 128 + n];
  }
  dst[idx] = f2bf(v);
}

// ---------------------------------------------------------------------------
// Counting sort of triplets by ji.
__global__ __launch_bounds__(256) void k_hist(const int* __restrict__ trip, int* __restrict__ cnt) {
  u32 t = blockIdx.x * 256 + threadIdx.x;
  atomicAdd(&cnt[trip[T_N + t]], 1);
}
__global__ __launch_bounds__(256) void k_scanA(const int* __restrict__ cnt,
                                               int* __restrict__ offsA, int* __restrict__ blksum) {
  __shared__ int s[256];
  u32 b = blockIdx.x, tid = threadIdx.x;
  int v = cnt[b * 256 + tid];
  s[tid] = v; __syncthreads();
  for (int d = 1; d < 256; d <<= 1) {
    int t = (tid >= (u32)d) ? s[tid - d] : 0;
    __syncthreads(); s[tid] += t; __syncthreads();
  }
  offsA[b * 256 + tid] = s[tid] - v;
  if (tid == 255) blksum[b] = s[255];
}
__global__ __launch_bounds__(512) void k_scanB(const int* __restrict__ blksum, int* __restrict__ blkoff) {
  __shared__ int s[512];
  u32 tid = threadIdx.x;
  int v = blksum[tid];
  s[tid] = v; __syncthreads();
  for (int d = 1; d < 512; d <<= 1) {
    int t = (tid >= (u32)d) ? s[tid - d] : 0;
    __syncthreads(); s[tid] += t; __syncthreads();
  }
  blkoff[tid] = s[tid] - v;
}
__global__ __launch_bounds__(256) void k_scanC(const int* __restrict__ offsA,
                                               const int* __restrict__ blkoff, int* __restrict__ offs_work) {
  u32 i = blockIdx.x * 256 + threadIdx.x;
  offs_work[i] = offsA[i] + blkoff[blockIdx.x];
}
__global__ __launch_bounds__(256) void k_place(const int* __restrict__ trip,
                                               int* __restrict__ offs_work, int* __restrict__ tsort) {
  u32 t = blockIdx.x * 256 + threadIdx.x;
  int e = trip[T_N + t];
  int p = atomicAdd(&offs_work[e], 1);
  tsort[p] = (int)t;
}

// ---------------------------------------------------------------------------
// S2: per-edge pre-GEMM.  [128 rows] x W2F(16 tiles) -> 256 cols.
__global__ __launch_bounds__(512, 2) void k_pre(
    const float* __restrict__ m, const float* __restrict__ rbf, const float* __restrict__ Wrbf,
    const float* __restrict__ bkj, const float* __restrict__ bji,
    const char* __restrict__ W2F, float* __restrict__ aggr, u16* __restrict__ ek) {
  extern __shared__ char lds[];
  char* ldsA = lds;                              // 32768
  float* ldsRbf = (float*)(lds + 32768);         // [128][6]
  float* ldsWr = (float*)(lds + 35840);          // [6][128]  -> total 38912
  const u32 tid = threadIdx.x, lane = tid & 63;
  const u32 r0 = blockIdx.x << 7;

#pragma unroll
  for (int it = 0; it < 8; ++it) {
    u32 q = tid + it * 512;
    u32 row = q >> 5, c4 = q & 31;
    f32x4 v = *(const f32x4*)(m + (size_t)(r0 + row) * 128 + c4 * 4);
    u32 c = c4 >> 1, half = c4 & 1;
    u32 w0 = (u32)f2bf(v[0]) | ((u32)f2bf(v[1]) << 16);
    u32 w1 = (u32)f2bf(v[2]) | ((u32)f2bf(v[3]) << 16);
    u32 ofs = (row << 8) + ((c ^ (row & 7)) << 4) + half * 8;
    *(u64*)(ldsA + ofs) = (u64)w0 | ((u64)w1 << 32);
  }
  for (u32 i = tid; i < 768; i += 512) ldsRbf[i] = rbf[(size_t)r0 * 6 + i];
  for (u32 i = tid; i < 768; i += 512) ldsWr[i] = Wrbf[i];
  __syncthreads();

  const u32 wid = tid >> 6, wm = wid >> 2, wn = wid & 3;
  const u32 rb = wm << 6, cb = wn << 6;
  f32x4 acc[4][4] = {};
  bf16x8 Bf[4][4];
#pragma unroll
  for (int ni = 0; ni < 4; ++ni)
#pragma unroll
    for (int ks = 0; ks < 4; ++ks) Bf[ni][ks] = ldfrag(W2F, wn * 4 + ni, ks, lane);
#pragma unroll
  for (int mi = 0; mi < 4; ++mi) {
    u32 row = rb + mi * 16 + (lane & 15);
    bf16x8 Af[4];
#pragma unroll
    for (int ks = 0; ks < 4; ++ks)
      Af[ks] = *(const bf16x8*)(ldsA + (row << 8) + ((((u32)(ks * 4) + (lane >> 4)) ^ (row & 7)) << 4));
#pragma unroll
    for (int ni = 0; ni < 4; ++ni)
#pragma unroll
      for (int ks = 0; ks < 4; ++ks) acc[mi][ni] = mfma16(Af[ks], Bf[ni][ks], acc[mi][ni]);
  }
#pragma unroll
  for (int mi = 0; mi < 4; ++mi) {
    u32 rloc = rb + mi * 16 + ((lane >> 4) << 2);
#pragma unroll
    for (int j = 0; j < 4; ++j) {
      u32 rl = rloc + j;
      size_t grow = r0 + rl;
#pragma unroll
      for (int ni = 0; ni < 4; ++ni) {
        u32 col = cb + ni * 16 + (lane & 15);
        float v = acc[mi][ni][j];
        if (col < 128) {
          aggr[grow * 128 + col] = silu_f(v + bji[col]);
        } else {
          u32 c2 = col - 128;
          float rw = 0.f;
#pragma unroll
          for (int q = 0; q < 6; ++q) rw += ldsRbf[rl * 6 + q] * ldsWr[q * 128 + c2];
          ek[grow * 128 + c2] = f2bf(silu_f(v + bkj[c2]) * rw);
        }
      }
    }
  }
}

// ---------------------------------------------------------------------------
// S3: sbf_proj = sbf @ W_sbf -> sp[T][8] f32 (coalesced).
__global__ __launch_bounds__(256) void k_sbf(
    const float* __restrict__ sbf, const float* __restrict__ Wsbf, float* __restrict__ sp) {
  extern __shared__ char lds[];
  float* s_lds = (float*)lds;              // 256*42 f32 = 43008 B
  float* w_lds = (float*)(lds + 43008);    // [42][8]
  const u32 tid = threadIdx.x;
  const u32 t0 = blockIdx.x << 8;
  for (u32 i = tid; i < 256 * 42; i += 256) s_lds[i] = sbf[(size_t)t0 * 42 + i];
  for (u32 i = tid; i < 336; i += 256) w_lds[i] = Wsbf[i];
  __syncthreads();
  float rv[42];
#pragma unroll
  for (int q = 0; q < 42; ++q) rv[q] = s_lds[tid * 42 + q];
  float o[8] = {0.f, 0.f, 0.f, 0.f, 0.f, 0.f, 0.f, 0.f};
#pragma unroll
  for (int q = 0; q < 42; ++q) {
    float r = rv[q];
#pragma unroll
    for (int c = 0; c < 8; ++c) o[c] += r * w_lds[q * 8 + c];
  }
  float* dst = sp + (size_t)(t0 + tid) * 8;
  f32x4 v0, v1;
#pragma unroll
  for (int j = 0; j < 4; ++j) { v0[j] = o[j]; v1[j] = o[4 + j]; }
  *(f32x4*)dst = v0;
  *(f32x4*)(dst + 4) = v1;
}

// ---------------------------------------------------------------------------
// S4 v4: run-compressed bilinear.  Per block 128 ji-sorted triplets.
//   Y_flat[run][b*128+h] = sum_{rows in run} sp[r][b] * x[r][h]   (VALU, LDS)
//   acc[run][n] = Y_flat[run][:] @ W_stack[1024][128]             (K=1024 MFMA)
//   atomic: aggr[ji(run)][n] += acc[run][n]
// 8x fewer MFMA FLOPs than per-triplet bilinear (T/E = 8 compression).
__global__ __launch_bounds__(256, 2) void k_bil(
    const int* __restrict__ trip, const char* __restrict__ ek,
    const float* __restrict__ sp, const char* __restrict__ WS,
    const int* __restrict__ tsort, float* __restrict__ aggr) {
  extern __shared__ char lds[];
  char* Xl = lds;                         // [128 rows][256B] swizzled bf16 (32768)
  char* Yt = lds + 32768;                 // Ytile [16][2048B] swizzled bf16 (32768)
  float* spT = (float*)(lds + 65536);     // [8][128] f32 (4096)
  int* jil = (int*)(lds + 69632);         // 128
  int* kjl = (int*)(lds + 70144);         // 128
  int* sc = (int*)(lds + 70656);          // 128 runid per row
  int* rstart = (int*)(lds + 71168);      // 128 (phase A/B: holds tv)
  int* scnt = (int*)(lds + 71680);        // 2   -> total 71688
  const u32 tid = threadIdx.x, lane = tid & 63, wid = tid >> 6;
  const u32 t0 = blockIdx.x << 7;

  // phase A: sorted indices
  if (tid < 128) {
    int tv = tsort[t0 + tid];
    kjl[tid] = trip[tv];
    jil[tid] = trip[T_N + tv];
    rstart[tid] = tv;                     // stash tv for sp gather
  }
  __syncthreads();

  // phase B: X gather (async) + sp row gather -> spT[b][r]
#pragma unroll
  for (int it = 0; it < 8; ++it) {
    u32 q = tid + it * 256, row = q >> 4, c = q & 15;
    gld_lds16(ek + (size_t)kjl[row] * 256 + ((c ^ (row & 7)) << 4), Xl + q * 16);
  }
  {
    u32 row = tid >> 1, h = tid & 1;
    int tv2 = rstart[row];
    f32x4 v = *(const f32x4*)(sp + (size_t)tv2 * 8 + h * 4);
#pragma unroll
    for (int j = 0; j < 4; ++j) spT[(h * 4 + j) * 128 + row] = v[j];
  }
  WAIT_VM0();
  __syncthreads();

  // phase C: ballot run-detect -> sc (runid per row), rstart (row of run start)
  int isS = 0;
  u32 pre = 0;
  if (tid < 128) {
    isS = (tid == 0) || (jil[tid] != jil[tid - 1]);
    u64 mask = __ballot(isS);
    pre = (u32)__popcll(mask & ((1ull << lane) - 1ull));
    if (lane == 0) scnt[wid] = (int)__popcll(mask);
  }
  __syncthreads();
  if (tid < 128) {
    u32 off = (wid == 1) ? (u32)scnt[0] : 0u;
    int rid = (int)(pre + off) + isS - 1;
    sc[tid] = rid;
    if (isS) rstart[rid] = (int)tid;
  }
  __syncthreads();
  const u32 nr = (u32)(scnt[0] + scnt[1]);

  // per-thread Y-build geometry: thread owns flat cols 4*tid..4*tid+3
  const u32 bb = tid >> 5;                 // b index 0..7
  const u32 h0 = (tid & 31) << 2;          // h base 0..124
  const u32 xchunk = h0 >> 3;              // 16B chunk of h0 within x row
  const u32 xhalf = ((h0 >> 2) & 1) * 8;   // 8B half
  const u32 ychunk0 = tid >> 1;            // Ytile 16B chunk for this thread's 8B
  const u32 yhalf = (tid & 1) * 8;

  const u32 mtiles = (nr + 15) >> 4;
  for (u32 mt = 0; mt < mtiles; ++mt) {
    const u32 run_lo = mt << 4;
    int r = rstart[run_lo];
    int r_hi = (run_lo + 16 < nr) ? rstart[run_lo + 16] : 128;
    // build Ytile rows 0..min(16, nr-run_lo)
    f32x4 s = {0.f, 0.f, 0.f, 0.f};
    for (; r < r_hi; ++r) {
      u32 xaddr = ((u32)r << 8) + ((xchunk ^ ((u32)r & 7)) << 4) + xhalf;
      u64 xv = *(const u64*)(Xl + xaddr);
      float spv = spT[bb * 128 + (u32)r];
      s[0] += spv * bf2f((u32)(xv & 0xffffu));
      s[1] += spv * bf2f((u32)((xv >> 16) & 0xffffu));
      s[2] += spv * bf2f((u32)((xv >> 32) & 0xffffu));
      s[3] += spv * bf2f((u32)(xv >> 48));
      int rid = sc[r];
      bool last = (r + 1 == r_hi) || (sc[r + 1] != rid);
      if (last) {
        u32 yr = (u32)rid - run_lo;        // 0..15
        u64 w = (u64)((u32)f2bf(s[0]) | ((u32)f2bf(s[1]) << 16))
              | ((u64)((u32)f2bf(s[2]) | ((u32)f2bf(s[3]) << 16)) << 32);
        *(u64*)(Yt + yr * 2048 + ((ychunk0 ^ (yr & 7)) << 4) + yhalf) = w;
        s = (f32x4){0.f, 0.f, 0.f, 0.f};
      }
    }
    __syncthreads();   // Ytile built

    // GEMM: M=16, N=128 (wave -> 2 ntiles), K=1024
    f32x4 a0 = {0.f, 0.f, 0.f, 0.f}, a1 = {0.f, 0.f, 0.f, 0.f};
    const u32 yrow = lane & 15;
    const u32 ksel = lane >> 4;
    const char* ws0 = WS + (size_t)(wid * 2) * 32768;
#pragma unroll
    for (u32 kc = 0; kc < 32; ++kc) {
      u32 chunk = (kc * 4 + ksel) ^ (yrow & 7);
      bf16x8 Af = *(const bf16x8*)(Yt + yrow * 2048 + (chunk << 4));
      bf16x8 B0 = *(const bf16x8*)(ws0 + kc * 1024 + lane * 16);
      bf16x8 B1 = *(const bf16x8*)(ws0 + 32768 + kc * 1024 + lane * 16);
      a0 = mfma16(Af, B0, a0);
      a1 = mfma16(Af, B1, a1);
    }
    // scatter: one atomic per (run, col)
    const u32 colb = lane & 15;
    const u32 rsel = (lane >> 4) << 2;
#pragma unroll
    for (int j = 0; j < 4; ++j) {
      u32 run = run_lo + rsel + (u32)j;
      if (run < nr) {
        int e = jil[rstart[run]];
        float* dst = aggr + (size_t)e * 128 + colb;
        unsafeAtomicAdd(dst + (wid * 2) * 16, a0[j]);
        unsafeAtomicAdd(dst + (wid * 2 + 1) * 16, a1[j]);
      }
    }
    __syncthreads();   // before next mtile overwrites Ytile
  }
}

// ---------------------------------------------------------------------------
// S5: fused residual chain (W staged to LDS, overlapped w/ epilogue).
__global__ __launch_bounds__(256, 2) void k_res(
    const float* __restrict__ aggr, const float* __restrict__ m,
    const char* __restrict__ rT,
    const float* __restrict__ rb1, const float* __restrict__ rb2,
    const float* __restrict__ rb3, const float* __restrict__ rb4,
    const float* __restrict__ bo, float* __restrict__ out) {
  extern __shared__ char lds[];
  char* ldsA = lds;
  char* ldsB = lds + 32768;
  const u32 tid = threadIdx.x, lane = tid & 63, wid = tid >> 6;
  const u32 r0 = blockIdx.x << 7;
  const u32 wm = wid >> 1, wn = wid & 1, rbw = wm << 6, cbw = wn << 6;
  const u32 lrow = (lane >> 4) << 2, lcol = lane & 15;

  auto stageB = [&](const char* WT) {
#pragma unroll
    for (int it = 0; it < 8; ++it) {
      u32 q = tid + it * 256, n = q >> 4, c = q & 15;
      gld_lds16(WT + n * 256 + ((c ^ (n & 7)) << 4), ldsB + q * 16);
    }
  };
  auto writeA = [&](u32 row, u32 col, float v) {
    *(u16*)(ldsA + (row << 8) + ((((col >> 3)) ^ (row & 7)) << 4) + (col & 7) * 2) = f2bf(v);
  };
  auto compute = [&](f32x4 (&acc)[4][4]) {
#pragma unroll
    for (int mi = 0; mi < 4; ++mi) {
      u32 row = rbw + mi * 16 + lcol;
      bf16x8 Af[4];
#pragma unroll
      for (int ks = 0; ks < 4; ++ks)
        Af[ks] = *(const bf16x8*)(ldsA + (row << 8) + ((((u32)(ks * 4) + (lane >> 4)) ^ (row & 7)) << 4));
#pragma unroll
      for (int ni = 0; ni < 4; ++ni) {
        u32 n = cbw + ni * 16 + lcol;
#pragma unroll
        for (int ks = 0; ks < 4; ++ks) {
          bf16x8 Bk = *(const bf16x8*)(ldsB + (n << 8) + ((((u32)(ks * 4) + (lane >> 4)) ^ (n & 7)) << 4));
          acc[mi][ni] = mfma16(Af[ks], Bk, acc[mi][ni]);
        }
      }
    }
  };
  auto zero = [&](f32x4 (&acc)[4][4]) {
#pragma unroll
    for (int a = 0; a < 4; ++a)
#pragma unroll
      for (int c = 0; c < 4; ++c) acc[a][c] = (f32x4){0.f, 0.f, 0.f, 0.f};
  };

  f32x4 xr[4][4];
#pragma unroll
  for (int mi = 0; mi < 4; ++mi)
#pragma unroll
    for (int j = 0; j < 4; ++j) {
      const float* src = aggr + (size_t)(r0 + rbw + mi * 16 + lrow + j) * 128 + cbw + lcol;
#pragma unroll
      for (int ni = 0; ni < 4; ++ni) xr[mi][ni][j] = src[ni * 16];
    }
  stageB(rT);
#pragma unroll
  for (int mi = 0; mi < 4; ++mi)
#pragma unroll
    for (int j = 0; j < 4; ++j) {
      u32 row = rbw + mi * 16 + lrow + j;
#pragma unroll
      for (int ni = 0; ni < 4; ++ni) writeA(row, cbw + ni * 16 + lcol, silu_f(xr[mi][ni][j]));
    }
  __syncthreads();

  f32x4 acc[4][4];
  zero(acc); compute(acc);
  __syncthreads();
#pragma unroll
  for (int mi = 0; mi < 4; ++mi)
#pragma unroll
    for (int j = 0; j < 4; ++j) {
      u32 row = rbw + mi * 16 + lrow + j;
#pragma unroll
      for (int ni = 0; ni < 4; ++ni) {
        u32 col = cbw + ni * 16 + lcol;
        writeA(row, col, silu_f(acc[mi][ni][j] + rb1[col]));
      }
    }
  stageB(rT + 32768);
  __syncthreads();

  zero(acc); compute(acc);
  __syncthreads();
#pragma unroll
  for (int mi = 0; mi < 4; ++mi)
#pragma unroll
    for (int j = 0; j < 4; ++j) {
      u32 row = rbw + mi * 16 + lrow + j;
#pragma unroll
      for (int ni = 0; ni < 4; ++ni) {
        u32 col = cbw + ni * 16 + lcol;
        xr[mi][ni][j] += acc[mi][ni][j] + rb2[col];
        writeA(row, col, silu_f(xr[mi][ni][j]));
      }
    }
  stageB(rT + 65536);
  __syncthreads();

  zero(acc); compute(acc);
  __syncthreads();
#pragma unroll
  for (int mi = 0; mi < 4; ++mi)
#pragma unroll
    for (int j = 0; j < 4; ++j) {
      u32 row = rbw + mi * 16 + lrow + j;
#pragma unroll
      for (int ni = 0; ni < 4; ++ni) {
        u32 col = cbw + ni * 16 + lcol;
        writeA(row, col, silu_f(acc[mi][ni][j] + rb3[col]));
      }
    }
  stageB(rT + 98304);
  __syncthreads();

  zero(acc); compute(acc);
  __syncthreads();
#pragma unroll
  for (int mi = 0; mi < 4; ++mi)
#pragma unroll
    for (int j = 0; j < 4; ++j) {
      u32 row = rbw + mi * 16 + lrow + j;
#pragma unroll
      for (int ni = 0; ni < 4; ++ni) {
        u32 col = cbw + ni * 16 + lcol;
        xr[mi][ni][j] += acc[mi][ni][j] + rb4[col];
        writeA(row, col, xr[mi][ni][j]);
      }
    }
  stageB(rT + 131072);
#pragma unroll
  for (int mi = 0; mi < 4; ++mi)
#pragma unroll
    for (int j = 0; j < 4; ++j) {
      const float* src = m + (size_t)(r0 + rbw + mi * 16 + lrow + j) * 128 + cbw + lcol;
#pragma unroll
      for (int ni = 0; ni < 4; ++ni) xr[mi][ni][j] = src[ni * 16];
    }
  __syncthreads();

  zero(acc); compute(acc);
#pragma unroll
  for (int mi = 0; mi < 4; ++mi)
#pragma unroll
    for (int j = 0; j < 4; ++j) {
      size_t grow = r0 + rbw + mi * 16 + lrow + j;
#pragma unroll
      for (int ni = 0; ni < 4; ++ni) {
        u32 col = cbw + ni * 16 + lcol;
        out[grow * 128 + col] = xr[mi][ni][j] + silu_f(acc[mi][ni][j] + bo[col]);
      }
    }
}

// ---------------------------------------------------------------------------
extern "C" void kernel_launch(void* const* d_in, const int* in_sizes, int n_in,
                              void* d_out, int out_size, void* d_ws, size_t ws_size,
                              hipStream_t stream) {
  const float* m = (const float*)d_in[0];
  const float* rbf = (const float*)d_in[1];
  const float* sbf = (const float*)d_in[2];
  const int* trip = (const int*)d_in[4];
  const float* Wrbf = (const float*)d_in[5];
  const float* Wsbf = (const float*)d_in[6];
  const float* bkj = (const float*)d_in[8];
  const float* bji = (const float*)d_in[10];
  const float* r1b1 = (const float*)d_in[13];
  const float* r1b2 = (const float*)d_in[15];
  const float* r2b1 = (const float*)d_in[17];
  const float* r2b2 = (const float*)d_in[19];
  const float* bout = (const float*)d_in[21];

  char* ws = (char*)d_ws;
  char* W2F = ws;                          // 65536 B (frag-major)
  char* WS = ws + 65536;                   // 262144 B (K=1024 stack frag-major)
  char* rT = ws + 327680;                  // 163840 B (plain [n][k])
  u16* ek = (u16*)(ws + 524288);           // E*128 bf16 (33.5 MB)
  float* sp = (float*)(ws + 34078720);     // T*8 f32 (33.5 MB)
  float* aggr = (float*)(ws + 67633152);   // E*128 f32 (67 MB)
  int* cnt = (int*)(ws + 134742016);       // 131072 int
  int* offsA = (int*)(ws + 135266304);     // 131072 int
  int* blksum = (int*)(ws + 135790592);    // 512 int
  int* blkoff = (int*)(ws + 135792640);    // 512 int
  int* offs_work = (int*)(ws + 135794688); // 131072 int
  int* tsort = (int*)(ws + 136318976);     // T int (4 MB)

  hipFuncSetAttribute((const void*)k_pre, hipFuncAttributeMaxDynamicSharedMemorySize, 38912);
  hipFuncSetAttribute((const void*)k_sbf, hipFuncAttributeMaxDynamicSharedMemorySize, 44352);
  hipFuncSetAttribute((const void*)k_bil, hipFuncAttributeMaxDynamicSharedMemorySize, 71936);
  hipFuncSetAttribute((const void*)k_res, hipFuncAttributeMaxDynamicSharedMemorySize, 65536);

  // triplet counting-sort by ji
  hipMemsetAsync(cnt, 0, 131072 * sizeof(int), stream);
  k_hist<<<4096, 256, 0, stream>>>(trip, cnt);
  k_scanA<<<512, 256, 0, stream>>>(cnt, offsA, blksum);
  k_scanB<<<1, 512, 0, stream>>>(blksum, blkoff);
  k_scanC<<<512, 256, 0, stream>>>(offsA, blkoff, offs_work);
  k_place<<<4096, 256, 0, stream>>>(trip, offs_work, tsort);

  k_transpose<<<960, 256, 0, stream>>>(
      (const float*)d_in[9], (const float*)d_in[7], (const float*)d_in[11],
      (const float*)d_in[12], (const float*)d_in[14], (const float*)d_in[16],
      (const float*)d_in[18], (const float*)d_in[20], (u16*)ws);
  k_pre<<<1024, 512, 38912, stream>>>(m, rbf, Wrbf, bkj, bji, W2F, aggr, ek);
  k_sbf<<<4096, 256, 44352, stream>>>(sbf, Wsbf, sp);
  k_bil<<<8192, 256, 71936, stream>>>(trip, (const char*)ek, sp, WS, tsort, aggr);
  k_res<<<1024, 256, 65536, stream>>>(aggr, m, rT, r1b1, r1b2, r2b1, r2b2, bout,
                                      (float*)d_out);
}

// Round 9
// 1057.769 us; speedup vs baseline: 1.0363x; 1.0363x over previous
//
#include <hip/hip_runtime.h>
#include <hip/hip_bf16.h>
#include <stdint.h>

typedef uint16_t u16;
typedef uint32_t u32;
typedef uint64_t u64;
typedef short bf16x8 __attribute__((ext_vector_type(8)));   // 8 bf16 in 4 VGPRs
typedef float f32x4 __attribute__((ext_vector_type(4)));
typedef u32 u32x4 __attribute__((ext_vector_type(4)));

#define E_N 131072
#define T_N 1048576

__device__ __forceinline__ float bf2f(u32 u) { return __builtin_bit_cast(float, u << 16); }
__device__ __forceinline__ u16 f2bf(float f) {
  u32 u = __builtin_bit_cast(u32, f);
  return (u16)((u + 0x7fffu + ((u >> 16) & 1u)) >> 16);   // RNE
}
__device__ __forceinline__ float silu_f(float x) { return x / (1.0f + __expf(-x)); }
__device__ __forceinline__ f32x4 mfma16(bf16x8 a, bf16x8 b, f32x4 c) {
  return __builtin_amdgcn_mfma_f32_16x16x32_bf16(a, b, c, 0, 0, 0);
}
__device__ __forceinline__ void gld_lds16(const void* g, void* l) {
  __builtin_amdgcn_global_load_lds((const __attribute__((address_space(1))) u32*)g,
                                   (__attribute__((address_space(3))) u32*)l, 16, 0, 0);
}
#define WAIT_VM0() do { asm volatile("s_waitcnt vmcnt(0)" ::: "memory"); \
                        __builtin_amdgcn_sched_barrier(0); } while (0)

// Fragment-major weight layout (tiles x 4 ksteps): frag is 1KB, lane*16B.
__device__ __forceinline__ bf16x8 ldfrag(const char* base, u32 tile, u32 ks, u32 lane) {
  return *(const bf16x8*)(base + (((tile << 2) + ks) << 10) + lane * 16);
}

// ---------------------------------------------------------------------------
// k_init = fused weight-transpose (blocks 0..959) + ji-histogram (960..5055).
//  region 0 (ws+0     ): W2F frag-major 16 tiles (n<128 Wji else Wkj)   32768
//  region 1 (ws+65536 ): WF  frag-major 8 b-slices x 8 tiles           131072
//  region 2 (ws+327680): rT  PLAIN [5][n=128][k=128]                    81920
__global__ __launch_bounds__(256) void k_init(
    const float* __restrict__ Wji, const float* __restrict__ Wkj, const float* __restrict__ Wbil,
    const float* __restrict__ w11, const float* __restrict__ w12,
    const float* __restrict__ w21, const float* __restrict__ w22, const float* __restrict__ wout,
    u16* __restrict__ dst, const int* __restrict__ trip, int* __restrict__ cnt) {
  u32 bid = blockIdx.x;
  if (bid >= 960) {
    u32 t = (bid - 960) * 256 + threadIdx.x;
    atomicAdd(&cnt[trip[T_N + t]], 1);
    return;
  }
  u32 idx = bid * 256 + threadIdx.x;
  if (idx >= 245760) return;
  float v;
  if (idx < 163840) {   // fragment-major regions
    u32 j = idx & 7, lane = (idx >> 3) & 63, ks = (idx >> 9) & 3;
    u32 k = ((ks << 2) + (lane >> 4)) * 8 + j;
    u32 nl = lane & 15;
    if (idx < 32768) {
      u32 g = idx >> 11;
      u32 n = g * 16 + nl;
      v = (n < 128) ? Wji[k * 128 + n] : Wkj[k * 128 + (n - 128)];
    } else {
      u32 q = idx - 32768;
      u32 g = (q >> 11) & 7, b = q >> 14;
      v = Wbil[k * 1024 + b * 128 + g * 16 + nl];
    }
  } else {              // plain [n][k] for k_res staging
    u32 q = idx - 163840;
    u32 r = q >> 14, n = (q >> 7) & 127, h = q & 127;
    const float* src = (r == 0) ? w11 : (r == 1) ? w12 : (r == 2) ? w21 : (r == 3) ? w22 : wout;
    v = src[h * 128 + n];
  }
  dst[idx] = f2bf(v);
}

// ---------------------------------------------------------------------------
// Prefix-scan chain for the counting sort.
__global__ __launch_bounds__(256) void k_scanA(const int* __restrict__ cnt,
                                               int* __restrict__ offsA, int* __restrict__ blksum) {
  __shared__ int s[256];
  u32 b = blockIdx.x, tid = threadIdx.x;
  int v = cnt[b * 256 + tid];
  s[tid] = v; __syncthreads();
  for (int d = 1; d < 256; d <<= 1) {
    int t = (tid >= (u32)d) ? s[tid - d] : 0;
    __syncthreads(); s[tid] += t; __syncthreads();
  }
  offsA[b * 256 + tid] = s[tid] - v;
  if (tid == 255) blksum[b] = s[255];
}
__global__ __launch_bounds__(512) void k_scanB(const int* __restrict__ blksum, int* __restrict__ blkoff) {
  __shared__ int s[512];
  u32 tid = threadIdx.x;
  int v = blksum[tid];
  s[tid] = v; __syncthreads();
  for (int d = 1; d < 512; d <<= 1) {
    int t = (tid >= (u32)d) ? s[tid - d] : 0;
    __syncthreads(); s[tid] += t; __syncthreads();
  }
  blkoff[tid] = s[tid] - v;
}
__global__ __launch_bounds__(256) void k_scanC(const int* __restrict__ offsA,
                                               const int* __restrict__ blkoff, int* __restrict__ offs_work) {
  u32 i = blockIdx.x * 256 + threadIdx.x;
  offs_work[i] = offsA[i] + blkoff[blockIdx.x];
}

// ---------------------------------------------------------------------------
// k_mid = fused: blocks 0..1023 -> per-edge pre-GEMM;
//                blocks 1024..3071 -> sort-placement + sbf projection -> srec.
//  srec[p] (32B): {int kj, int ji, bf16 sp[8], pad} at ji-sorted position p.
__global__ __launch_bounds__(512) void k_mid(
    const float* __restrict__ m, const float* __restrict__ rbf, const float* __restrict__ Wrbf,
    const float* __restrict__ bkj, const float* __restrict__ bji,
    const char* __restrict__ W2F, float* __restrict__ aggr, u16* __restrict__ ek,
    const int* __restrict__ trip, const float* __restrict__ sbf, const float* __restrict__ Wsbf,
    int* __restrict__ offs_work, char* __restrict__ srec) {
  const u32 tid = threadIdx.x;
  if (blockIdx.x >= 1024) {
    // ---- placement + sbf projection ----
    u32 t = (blockIdx.x - 1024) * 512 + tid;
    int kj = trip[t], ji = trip[T_N + t];
    int p = atomicAdd(&offs_work[ji], 1);
    float o[8] = {0.f, 0.f, 0.f, 0.f, 0.f, 0.f, 0.f, 0.f};
    const float* sr = sbf + (size_t)t * 42;
#pragma unroll
    for (int q = 0; q < 42; ++q) {
      float r = sr[q];
#pragma unroll
      for (int c = 0; c < 8; ++c) o[c] += r * Wsbf[q * 8 + c];   // Wsbf scalar-cached
    }
    u32x4 r0, r1;
    r0[0] = (u32)kj; r0[1] = (u32)ji;
    r0[2] = (u32)f2bf(o[0]) | ((u32)f2bf(o[1]) << 16);
    r0[3] = (u32)f2bf(o[2]) | ((u32)f2bf(o[3]) << 16);
    r1[0] = (u32)f2bf(o[4]) | ((u32)f2bf(o[5]) << 16);
    r1[1] = (u32)f2bf(o[6]) | ((u32)f2bf(o[7]) << 16);
    r1[2] = 0; r1[3] = 0;
    *(u32x4*)(srec + (size_t)p * 32) = r0;
    *(u32x4*)(srec + (size_t)p * 32 + 16) = r1;
    return;
  }
  // ---- per-edge pre-GEMM: [128 rows] x W2F(16 tiles) -> 256 cols ----
  extern __shared__ char lds[];
  char* ldsA = lds;                              // 32768
  float* ldsRbf = (float*)(lds + 32768);         // [128][6]
  float* ldsWr = (float*)(lds + 35840);          // [6][128]  -> total 38912
  const u32 lane = tid & 63;
  const u32 r0_ = blockIdx.x << 7;

#pragma unroll
  for (int it = 0; it < 8; ++it) {
    u32 q = tid + it * 512;
    u32 row = q >> 5, c4 = q & 31;
    f32x4 v = *(const f32x4*)(m + (size_t)(r0_ + row) * 128 + c4 * 4);
    u32 c = c4 >> 1, half = c4 & 1;
    u32 w0 = (u32)f2bf(v[0]) | ((u32)f2bf(v[1]) << 16);
    u32 w1 = (u32)f2bf(v[2]) | ((u32)f2bf(v[3]) << 16);
    u32 ofs = (row << 8) + ((c ^ (row & 7)) << 4) + half * 8;
    *(u64*)(ldsA + ofs) = (u64)w0 | ((u64)w1 << 32);
  }
  for (u32 i = tid; i < 768; i += 512) ldsRbf[i] = rbf[(size_t)r0_ * 6 + i];
  for (u32 i = tid; i < 768; i += 512) ldsWr[i] = Wrbf[i];
  __syncthreads();

  const u32 wid = tid >> 6, wm = wid >> 2, wn = wid & 3;
  const u32 rb = wm << 6, cb = wn << 6;
  f32x4 acc[4][4] = {};
  bf16x8 Bf[4][4];
#pragma unroll
  for (int ni = 0; ni < 4; ++ni)
#pragma unroll
    for (int ks = 0; ks < 4; ++ks) Bf[ni][ks] = ldfrag(W2F, wn * 4 + ni, ks, lane);
#pragma unroll
  for (int mi = 0; mi < 4; ++mi) {
    u32 row = rb + mi * 16 + (lane & 15);
    bf16x8 Af[4];
#pragma unroll
    for (int ks = 0; ks < 4; ++ks)
      Af[ks] = *(const bf16x8*)(ldsA + (row << 8) + ((((u32)(ks * 4) + (lane >> 4)) ^ (row & 7)) << 4));
#pragma unroll
    for (int ni = 0; ni < 4; ++ni)
#pragma unroll
      for (int ks = 0; ks < 4; ++ks) acc[mi][ni] = mfma16(Af[ks], Bf[ni][ks], acc[mi][ni]);
  }
#pragma unroll
  for (int mi = 0; mi < 4; ++mi) {
    u32 rloc = rb + mi * 16 + ((lane >> 4) << 2);
#pragma unroll
    for (int j = 0; j < 4; ++j) {
      u32 rl = rloc + j;
      size_t grow = r0_ + rl;
#pragma unroll
      for (int ni = 0; ni < 4; ++ni) {
        u32 col = cb + ni * 16 + (lane & 15);
        float v = acc[mi][ni][j];
        if (col < 128) {
          aggr[grow * 128 + col] = silu_f(v + bji[col]);
        } else {
          u32 c2 = col - 128;
          float rw = 0.f;
#pragma unroll
          for (int q = 0; q < 6; ++q) rw += ldsRbf[rl * 6 + q] * ldsWr[q * 128 + c2];
          ek[grow * 128 + c2] = f2bf(silu_f(v + bkj[c2]) * rw);
        }
      }
    }
  }
}

// ---------------------------------------------------------------------------
// S4 v5 (r7 structure + srec): per block 128 ji-sorted triplets.
//   srec coalesced read -> kjl/jil/spT;  X gather -> LDS -> regs;
//   W direct-global frag-major (barrier-free b-loop);
//   acc -> bf16 msg (overlay X); ballot run-detect; (run,col) task reduction.
__global__ __launch_bounds__(256, 3) void k_bil(
    const char* __restrict__ ek, const char* __restrict__ srec,
    const char* __restrict__ WF, float* __restrict__ aggr) {
  extern __shared__ char lds[];
  char* Xl = lds;                         // [128 rows][256B] swizzled bf16 (32768)
  u16* msg16 = (u16*)lds;                 // [128][128] bf16 overlay (32768)
  float* spT = (float*)(lds + 32768);     // [8][128] f32 (4096)
  int* jil = (int*)(lds + 36864);         // 128
  int* kjl = (int*)(lds + 37376);         // 128
  int* rstart = (int*)(lds + 37888);      // 128
  int* scnt = (int*)(lds + 38400);        // 2   -> total 38408
  const u32 tid = threadIdx.x, lane = tid & 63, wid = tid >> 6;
  const u32 wm = wid >> 1, wn = wid & 1, rb = wm << 6, cb = wn << 6;
  const u32 t0 = blockIdx.x << 7;

  // phase A: coalesced srec read -> indices + spT
  if (tid < 128) {
    const char* rp = srec + (size_t)(t0 + tid) * 32;
    u32x4 a = *(const u32x4*)rp;
    u32 c0 = *(const u32*)(rp + 16);
    u32 c1 = *(const u32*)(rp + 20);
    kjl[tid] = (int)a[0];
    jil[tid] = (int)a[1];
    spT[0 * 128 + tid] = bf2f(a[2] & 0xffffu);
    spT[1 * 128 + tid] = bf2f(a[2] >> 16);
    spT[2 * 128 + tid] = bf2f(a[3] & 0xffffu);
    spT[3 * 128 + tid] = bf2f(a[3] >> 16);
    spT[4 * 128 + tid] = bf2f(c0 & 0xffffu);
    spT[5 * 128 + tid] = bf2f(c0 >> 16);
    spT[6 * 128 + tid] = bf2f(c1 & 0xffffu);
    spT[7 * 128 + tid] = bf2f(c1 >> 16);
  }
  __syncthreads();

  // phase B: X gather (async)
#pragma unroll
  for (int it = 0; it < 8; ++it) {
    u32 q = tid + it * 256, row = q >> 4, c = q & 15;
    gld_lds16(ek + (size_t)kjl[row] * 256 + ((c ^ (row & 7)) << 4), Xl + q * 16);
  }
  // run-detect overlaps the gather latency
  int isS = 0;
  u32 pre = 0;
  if (tid < 128) {
    isS = (tid == 0) || (jil[tid] != jil[tid - 1]);
    u64 mask = __ballot(isS);
    pre = (u32)__popcll(mask & ((1ull << lane) - 1ull));
    if (lane == 0) scnt[wid] = (int)__popcll(mask);
  }
  WAIT_VM0();
  __syncthreads();
  if (tid < 128 && isS) {
    u32 off = (wid == 1) ? (u32)scnt[0] : 0u;
    rstart[pre + off] = (int)tid;
  }

  // phase C: hoist X fragments to registers
  bf16x8 Afr[4][4];
#pragma unroll
  for (int mi = 0; mi < 4; ++mi) {
    u32 row = rb + mi * 16 + (lane & 15);
#pragma unroll
    for (int ks = 0; ks < 4; ++ks)
      Afr[mi][ks] = *(const bf16x8*)(Xl + (row << 8) + ((((u32)(ks * 4) + (lane >> 4)) ^ (row & 7)) << 4));
  }
  __syncthreads();   // all waves hoisted + rstart visible; X region reusable as msg

  // phase D: barrier-free b-loop, W fragments direct from global (L2-hot)
  f32x4 acc[4][4] = {};
  for (int b = 0; b < 8; ++b) {
    const char* wb = WF + (size_t)b * 32768;
    bf16x8 Bf[4][4];
#pragma unroll
    for (int ni = 0; ni < 4; ++ni)
#pragma unroll
      for (int ks = 0; ks < 4; ++ks) Bf[ni][ks] = ldfrag(wb, wn * 4 + ni, ks, lane);
#pragma unroll
    for (int mi = 0; mi < 4; ++mi) {
      f32x4 s4 = *(const f32x4*)(spT + b * 128 + rb + mi * 16 + ((lane >> 4) << 2));
#pragma unroll
      for (int ni = 0; ni < 4; ++ni) {
        f32x4 p = {0.f, 0.f, 0.f, 0.f};
#pragma unroll
        for (int ks = 0; ks < 4; ++ks) p = mfma16(Afr[mi][ks], Bf[ni][ks], p);
        acc[mi][ni] += s4 * p;
      }
    }
  }

  // phase E: spill acc -> bf16 msg (overlay X)
#pragma unroll
  for (int mi = 0; mi < 4; ++mi) {
    u32 rloc = rb + mi * 16 + ((lane >> 4) << 2);
#pragma unroll
    for (int j = 0; j < 4; ++j) {
      u16* drow = msg16 + (size_t)(rloc + j) * 128 + cb + (lane & 15);
#pragma unroll
      for (int ni = 0; ni < 4; ++ni) drow[ni * 16] = f2bf(acc[mi][ni][j]);
    }
  }
  __syncthreads();

  // phase F: one atomic per (run, col), contiguous cols per wave
  const u32 nr = (u32)(scnt[0] + scnt[1]);
  for (u32 task = tid; task < nr * 128; task += 256) {
    u32 run = task >> 7, col = task & 127;
    int ra = rstart[run];
    int rz = (run + 1 < nr) ? rstart[run + 1] : 128;
    float s = 0.f;
    for (int r = ra; r < rz; ++r) s += bf2f(msg16[(size_t)r * 128 + col]);
    unsafeAtomicAdd(&aggr[(size_t)jil[ra] * 128 + col], s);
  }
}

// ---------------------------------------------------------------------------
// S5: fused residual chain (W staged to LDS, overlapped w/ epilogue).
__global__ __launch_bounds__(256, 2) void k_res(
    const float* __restrict__ aggr, const float* __restrict__ m,
    const char* __restrict__ rT,
    const float* __restrict__ rb1, const float* __restrict__ rb2,
    const float* __restrict__ rb3, const float* __restrict__ rb4,
    const float* __restrict__ bo, float* __restrict__ out) {
  extern __shared__ char lds[];
  char* ldsA = lds;
  char* ldsB = lds + 32768;
  const u32 tid = threadIdx.x, lane = tid & 63, wid = tid >> 6;
  const u32 r0 = blockIdx.x << 7;
  const u32 wm = wid >> 1, wn = wid & 1, rbw = wm << 6, cbw = wn << 6;
  const u32 lrow = (lane >> 4) << 2, lcol = lane & 15;

  auto stageB = [&](const char* WT) {
#pragma unroll
    for (int it = 0; it < 8; ++it) {
      u32 q = tid + it * 256, n = q >> 4, c = q & 15;
      gld_lds16(WT + n * 256 + ((c ^ (n & 7)) << 4), ldsB + q * 16);
    }
  };
  auto writeA = [&](u32 row, u32 col, float v) {
    *(u16*)(ldsA + (row << 8) + ((((col >> 3)) ^ (row & 7)) << 4) + (col & 7) * 2) = f2bf(v);
  };
  auto compute = [&](f32x4 (&acc)[4][4]) {
#pragma unroll
    for (int mi = 0; mi < 4; ++mi) {
      u32 row = rbw + mi * 16 + lcol;
      bf16x8 Af[4];
#pragma unroll
      for (int ks = 0; ks < 4; ++ks)
        Af[ks] = *(const bf16x8*)(ldsA + (row << 8) + ((((u32)(ks * 4) + (lane >> 4)) ^ (row & 7)) << 4));
#pragma unroll
      for (int ni = 0; ni < 4; ++ni) {
        u32 n = cbw + ni * 16 + lcol;
#pragma unroll
        for (int ks = 0; ks < 4; ++ks) {
          bf16x8 Bk = *(const bf16x8*)(ldsB + (n << 8) + ((((u32)(ks * 4) + (lane >> 4)) ^ (n & 7)) << 4));
          acc[mi][ni] = mfma16(Af[ks], Bk, acc[mi][ni]);
        }
      }
    }
  };
  auto zero = [&](f32x4 (&acc)[4][4]) {
#pragma unroll
    for (int a = 0; a < 4; ++a)
#pragma unroll
      for (int c = 0; c < 4; ++c) acc[a][c] = (f32x4){0.f, 0.f, 0.f, 0.f};
  };

  f32x4 xr[4][4];
#pragma unroll
  for (int mi = 0; mi < 4; ++mi)
#pragma unroll
    for (int j = 0; j < 4; ++j) {
      const float* src = aggr + (size_t)(r0 + rbw + mi * 16 + lrow + j) * 128 + cbw + lcol;
#pragma unroll
      for (int ni = 0; ni < 4; ++ni) xr[mi][ni][j] = src[ni * 16];
    }
  stageB(rT);
#pragma unroll
  for (int mi = 0; mi < 4; ++mi)
#pragma unroll
    for (int j = 0; j < 4; ++j) {
      u32 row = rbw + mi * 16 + lrow + j;
#pragma unroll
      for (int ni = 0; ni < 4; ++ni) writeA(row, cbw + ni * 16 + lcol, silu_f(xr[mi][ni][j]));
    }
  __syncthreads();

  f32x4 acc[4][4];
  zero(acc); compute(acc);
  __syncthreads();
#pragma unroll
  for (int mi = 0; mi < 4; ++mi)
#pragma unroll
    for (int j = 0; j < 4; ++j) {
      u32 row = rbw + mi * 16 + lrow + j;
#pragma unroll
      for (int ni = 0; ni < 4; ++ni) {
        u32 col = cbw + ni * 16 + lcol;
        writeA(row, col, silu_f(acc[mi][ni][j] + rb1[col]));
      }
    }
  stageB(rT + 32768);
  __syncthreads();

  zero(acc); compute(acc);
  __syncthreads();
#pragma unroll
  for (int mi = 0; mi < 4; ++mi)
#pragma unroll
    for (int j = 0; j < 4; ++j) {
      u32 row = rbw + mi * 16 + lrow + j;
#pragma unroll
      for (int ni = 0; ni < 4; ++ni) {
        u32 col = cbw + ni * 16 + lcol;
        xr[mi][ni][j] += acc[mi][ni][j] + rb2[col];
        writeA(row, col, silu_f(xr[mi][ni][j]));
      }
    }
  stageB(rT + 65536);
  __syncthreads();

  zero(acc); compute(acc);
  __syncthreads();
#pragma unroll
  for (int mi = 0; mi < 4; ++mi)
#pragma unroll
    for (int j = 0; j < 4; ++j) {
      u32 row = rbw + mi * 16 + lrow + j;
#pragma unroll
      for (int ni = 0; ni < 4; ++ni) {
        u32 col = cbw + ni * 16 + lcol;
        writeA(row, col, silu_f(acc[mi][ni][j] + rb3[col]));
      }
    }
  stageB(rT + 98304);
  __syncthreads();

  zero(acc); compute(acc);
  __syncthreads();
#pragma unroll
  for (int mi = 0; mi < 4; ++mi)
#pragma unroll
    for (int j = 0; j < 4; ++j) {
      u32 row = rbw + mi * 16 + lrow + j;
#pragma unroll
      for (int ni = 0; ni < 4; ++ni) {
        u32 col = cbw + ni * 16 + lcol;
        xr[mi][ni][j] += acc[mi][ni][j] + rb4[col];
        writeA(row, col, xr[mi][ni][j]);
      }
    }
  stageB(rT + 131072);
#pragma unroll
  for (int mi = 0; mi < 4; ++mi)
#pragma unroll
    for (int j = 0; j < 4; ++j) {
      const float* src = m + (size_t)(r0 + rbw + mi * 16 + lrow + j) * 128 + cbw + lcol;
#pragma unroll
      for (int ni = 0; ni < 4; ++ni) xr[mi][ni][j] = src[ni * 16];
    }
  __syncthreads();

  zero(acc); compute(acc);
#pragma unroll
  for (int mi = 0; mi < 4; ++mi)
#pragma unroll
    for (int j = 0; j < 4; ++j) {
      size_t grow = r0 + rbw + mi * 16 + lrow + j;
#pragma unroll
      for (int ni = 0; ni < 4; ++ni) {
        u32 col = cbw + ni * 16 + lcol;
        out[grow * 128 + col] = xr[mi][ni][j] + silu_f(acc[mi][ni][j] + bo[col]);
      }
    }
}

// ---------------------------------------------------------------------------
extern "C" void kernel_launch(void* const* d_in, const int* in_sizes, int n_in,
                              void* d_out, int out_size, void* d_ws, size_t ws_size,
                              hipStream_t stream) {
  const float* m = (const float*)d_in[0];
  const float* rbf = (const float*)d_in[1];
  const float* sbf = (const float*)d_in[2];
  const int* trip = (const int*)d_in[4];
  const float* Wrbf = (const float*)d_in[5];
  const float* Wsbf = (const float*)d_in[6];
  const float* bkj = (const float*)d_in[8];
  const float* bji = (const float*)d_in[10];
  const float* r1b1 = (const float*)d_in[13];
  const float* r1b2 = (const float*)d_in[15];
  const float* r2b1 = (const float*)d_in[17];
  const float* r2b2 = (const float*)d_in[19];
  const float* bout = (const float*)d_in[21];

  char* ws = (char*)d_ws;
  char* W2F = ws;                          // 65536 B (frag-major)
  char* WF = ws + 65536;                   // 262144 B (frag-major)
  char* rT = ws + 327680;                  // 163840 B (plain [n][k])
  u16* ek = (u16*)(ws + 524288);           // E*128 bf16 (33.5 MB)
  char* srec = ws + 34078720;              // T*32B sorted records (33.5 MB)
  float* aggr = (float*)(ws + 67633152);   // E*128 f32 (67 MB)
  int* cnt = (int*)(ws + 134742016);       // 131072 int
  int* offsA = (int*)(ws + 135266304);     // 131072 int
  int* blksum = (int*)(ws + 135790592);    // 512 int
  int* blkoff = (int*)(ws + 135792640);    // 512 int
  int* offs_work = (int*)(ws + 135794688); // 131072 int

  hipFuncSetAttribute((const void*)k_mid, hipFuncAttributeMaxDynamicSharedMemorySize, 38912);
  hipFuncSetAttribute((const void*)k_bil, hipFuncAttributeMaxDynamicSharedMemorySize, 38912);
  hipFuncSetAttribute((const void*)k_res, hipFuncAttributeMaxDynamicSharedMemorySize, 65536);

  hipMemsetAsync(cnt, 0, 131072 * sizeof(int), stream);
  k_init<<<5056, 256, 0, stream>>>(
      (const float*)d_in[9], (const float*)d_in[7], (const float*)d_in[11],
      (const float*)d_in[12], (const float*)d_in[14], (const float*)d_in[16],
      (const float*)d_in[18], (const float*)d_in[20], (u16*)ws, trip, cnt);
  k_scanA<<<512, 256, 0, stream>>>(cnt, offsA, blksum);
  k_scanB<<<1, 512, 0, stream>>>(blksum, blkoff);
  k_scanC<<<512, 256, 0, stream>>>(offsA, blkoff, offs_work);
  k_mid<<<3072, 512, 38912, stream>>>(m, rbf, Wrbf, bkj, bji, W2F, aggr, ek,
                                      trip, sbf, Wsbf, offs_work, srec);
  k_bil<<<8192, 256, 38912, stream>>>((const char*)ek, (const char*)srec, WF, aggr);
  k_res<<<1024, 256, 65536, stream>>>(aggr, m, rT, r1b1, r1b2, r2b1, r2b2, bout,
                                      (float*)d_out);
}

// Round 10
// 782.925 us; speedup vs baseline: 1.4000x; 1.3510x over previous
//
#include <hip/hip_runtime.h>
#include <hip/hip_bf16.h>
#include <stdint.h>

typedef uint16_t u16;
typedef uint32_t u32;
typedef uint64_t u64;
typedef short bf16x8 __attribute__((ext_vector_type(8)));   // 8 bf16 in 4 VGPRs
typedef float f32x4 __attribute__((ext_vector_type(4)));
typedef u32 u32x4 __attribute__((ext_vector_type(4)));

#define E_N 131072
#define T_N 1048576

__device__ __forceinline__ float bf2f(u32 u) { return __builtin_bit_cast(float, u << 16); }
__device__ __forceinline__ u16 f2bf(float f) {
  u32 u = __builtin_bit_cast(u32, f);
  return (u16)((u + 0x7fffu + ((u >> 16) & 1u)) >> 16);   // RNE
}
__device__ __forceinline__ float silu_f(float x) { return x / (1.0f + __expf(-x)); }
__device__ __forceinline__ f32x4 mfma16(bf16x8 a, bf16x8 b, f32x4 c) {
  return __builtin_amdgcn_mfma_f32_16x16x32_bf16(a, b, c, 0, 0, 0);
}
__device__ __forceinline__ void gld_lds16(const void* g, void* l) {
  __builtin_amdgcn_global_load_lds((const __attribute__((address_space(1))) u32*)g,
                                   (__attribute__((address_space(3))) u32*)l, 16, 0, 0);
}
#define WAIT_VM0() do { asm volatile("s_waitcnt vmcnt(0)" ::: "memory"); \
                        __builtin_amdgcn_sched_barrier(0); } while (0)

// Fragment-major weight layout (tiles x 4 ksteps): frag is 1KB, lane*16B.
__device__ __forceinline__ bf16x8 ldfrag(const char* base, u32 tile, u32 ks, u32 lane) {
  return *(const bf16x8*)(base + (((tile << 2) + ks) << 10) + lane * 16);
}

// ---------------------------------------------------------------------------
// k_init = fused weight-transpose (blocks 0..959) + ji-histogram (960..5055).
__global__ __launch_bounds__(256) void k_init(
    const float* __restrict__ Wji, const float* __restrict__ Wkj, const float* __restrict__ Wbil,
    const float* __restrict__ w11, const float* __restrict__ w12,
    const float* __restrict__ w21, const float* __restrict__ w22, const float* __restrict__ wout,
    u16* __restrict__ dst, const int* __restrict__ trip, int* __restrict__ cnt) {
  u32 bid = blockIdx.x;
  if (bid >= 960) {
    u32 t = (bid - 960) * 256 + threadIdx.x;
    atomicAdd(&cnt[trip[T_N + t]], 1);
    return;
  }
  u32 idx = bid * 256 + threadIdx.x;
  if (idx >= 245760) return;
  float v;
  if (idx < 163840) {   // fragment-major regions
    u32 j = idx & 7, lane = (idx >> 3) & 63, ks = (idx >> 9) & 3;
    u32 k = ((ks << 2) + (lane >> 4)) * 8 + j;
    u32 nl = lane & 15;
    if (idx < 32768) {
      u32 g = idx >> 11;
      u32 n = g * 16 + nl;
      v = (n < 128) ? Wji[k * 128 + n] : Wkj[k * 128 + (n - 128)];
    } else {
      u32 q = idx - 32768;
      u32 g = (q >> 11) & 7, b = q >> 14;
      v = Wbil[k * 1024 + b * 128 + g * 16 + nl];
    }
  } else {              // plain [n][k] for k_res staging
    u32 q = idx - 163840;
    u32 r = q >> 14, n = (q >> 7) & 127, h = q & 127;
    const float* src = (r == 0) ? w11 : (r == 1) ? w12 : (r == 2) ? w21 : (r == 3) ? w22 : wout;
    v = src[h * 128 + n];
  }
  dst[idx] = f2bf(v);
}

// ---------------------------------------------------------------------------
// Prefix-scan chain for the counting sort.
__global__ __launch_bounds__(256) void k_scanA(const int* __restrict__ cnt,
                                               int* __restrict__ offsA, int* __restrict__ blksum) {
  __shared__ int s[256];
  u32 b = blockIdx.x, tid = threadIdx.x;
  int v = cnt[b * 256 + tid];
  s[tid] = v; __syncthreads();
  for (int d = 1; d < 256; d <<= 1) {
    int t = (tid >= (u32)d) ? s[tid - d] : 0;
    __syncthreads(); s[tid] += t; __syncthreads();
  }
  offsA[b * 256 + tid] = s[tid] - v;
  if (tid == 255) blksum[b] = s[255];
}
__global__ __launch_bounds__(512) void k_scanB(const int* __restrict__ blksum, int* __restrict__ blkoff) {
  __shared__ int s[512];
  u32 tid = threadIdx.x;
  int v = blksum[tid];
  s[tid] = v; __syncthreads();
  for (int d = 1; d < 512; d <<= 1) {
    int t = (tid >= (u32)d) ? s[tid - d] : 0;
    __syncthreads(); s[tid] += t; __syncthreads();
  }
  blkoff[tid] = s[tid] - v;
}
__global__ __launch_bounds__(256) void k_scanC(const int* __restrict__ offsA,
                                               const int* __restrict__ blkoff, int* __restrict__ offs_work) {
  u32 i = blockIdx.x * 256 + threadIdx.x;
  offs_work[i] = offsA[i] + blkoff[blockIdx.x];
}

// ---------------------------------------------------------------------------
// k_mid = fused: blocks 0..1023 -> per-edge pre-GEMM;
//                blocks 1024..3071 -> sort-placement + sbf projection -> srec.
//  srec[p] (32B): {int kj, int ji, bf16 sp[8], pad} at ji-sorted position p.
__global__ __launch_bounds__(512) void k_mid(
    const float* __restrict__ m, const float* __restrict__ rbf, const float* __restrict__ Wrbf,
    const float* __restrict__ bkj, const float* __restrict__ bji,
    const char* __restrict__ W2F, float* __restrict__ aggr, u16* __restrict__ ek,
    const int* __restrict__ trip, const float* __restrict__ sbf, const float* __restrict__ Wsbf,
    int* __restrict__ offs_work, char* __restrict__ srec) {
  const u32 tid = threadIdx.x;
  if (blockIdx.x >= 1024) {
    // ---- placement + sbf projection ----
    u32 t = (blockIdx.x - 1024) * 512 + tid;
    int kj = trip[t], ji = trip[T_N + t];
    int p = atomicAdd(&offs_work[ji], 1);
    float o[8] = {0.f, 0.f, 0.f, 0.f, 0.f, 0.f, 0.f, 0.f};
    const float* sr = sbf + (size_t)t * 42;
#pragma unroll
    for (int q = 0; q < 42; ++q) {
      float r = sr[q];
#pragma unroll
      for (int c = 0; c < 8; ++c) o[c] += r * Wsbf[q * 8 + c];   // Wsbf scalar-cached
    }
    u32x4 r0, r1;
    r0[0] = (u32)kj; r0[1] = (u32)ji;
    r0[2] = (u32)f2bf(o[0]) | ((u32)f2bf(o[1]) << 16);
    r0[3] = (u32)f2bf(o[2]) | ((u32)f2bf(o[3]) << 16);
    r1[0] = (u32)f2bf(o[4]) | ((u32)f2bf(o[5]) << 16);
    r1[1] = (u32)f2bf(o[6]) | ((u32)f2bf(o[7]) << 16);
    r1[2] = 0; r1[3] = 0;
    *(u32x4*)(srec + (size_t)p * 32) = r0;
    *(u32x4*)(srec + (size_t)p * 32 + 16) = r1;
    return;
  }
  // ---- per-edge pre-GEMM: [128 rows] x W2F(16 tiles) -> 256 cols ----
  extern __shared__ char lds[];
  char* ldsA = lds;                              // 32768
  float* ldsRbf = (float*)(lds + 32768);         // [128][6]
  float* ldsWr = (float*)(lds + 35840);          // [6][128]  -> total 38912
  const u32 lane = tid & 63;
  const u32 r0_ = blockIdx.x << 7;

#pragma unroll
  for (int it = 0; it < 8; ++it) {
    u32 q = tid + it * 512;
    u32 row = q >> 5, c4 = q & 31;
    f32x4 v = *(const f32x4*)(m + (size_t)(r0_ + row) * 128 + c4 * 4);
    u32 c = c4 >> 1, half = c4 & 1;
    u32 w0 = (u32)f2bf(v[0]) | ((u32)f2bf(v[1]) << 16);
    u32 w1 = (u32)f2bf(v[2]) | ((u32)f2bf(v[3]) << 16);
    u32 ofs = (row << 8) + ((c ^ (row & 7)) << 4) + half * 8;
    *(u64*)(ldsA + ofs) = (u64)w0 | ((u64)w1 << 32);
  }
  for (u32 i = tid; i < 768; i += 512) ldsRbf[i] = rbf[(size_t)r0_ * 6 + i];
  for (u32 i = tid; i < 768; i += 512) ldsWr[i] = Wrbf[i];
  __syncthreads();

  const u32 wid = tid >> 6, wm = wid >> 2, wn = wid & 3;
  const u32 rb = wm << 6, cb = wn << 6;
  f32x4 acc[4][4] = {};
  bf16x8 Bf[4][4];
#pragma unroll
  for (int ni = 0; ni < 4; ++ni)
#pragma unroll
    for (int ks = 0; ks < 4; ++ks) Bf[ni][ks] = ldfrag(W2F, wn * 4 + ni, ks, lane);
#pragma unroll
  for (int mi = 0; mi < 4; ++mi) {
    u32 row = rb + mi * 16 + (lane & 15);
    bf16x8 Af[4];
#pragma unroll
    for (int ks = 0; ks < 4; ++ks)
      Af[ks] = *(const bf16x8*)(ldsA + (row << 8) + ((((u32)(ks * 4) + (lane >> 4)) ^ (row & 7)) << 4));
#pragma unroll
    for (int ni = 0; ni < 4; ++ni)
#pragma unroll
      for (int ks = 0; ks < 4; ++ks) acc[mi][ni] = mfma16(Af[ks], Bf[ni][ks], acc[mi][ni]);
  }
#pragma unroll
  for (int mi = 0; mi < 4; ++mi) {
    u32 rloc = rb + mi * 16 + ((lane >> 4) << 2);
#pragma unroll
    for (int j = 0; j < 4; ++j) {
      u32 rl = rloc + j;
      size_t grow = r0_ + rl;
#pragma unroll
      for (int ni = 0; ni < 4; ++ni) {
        u32 col = cb + ni * 16 + (lane & 15);
        float v = acc[mi][ni][j];
        if (col < 128) {
          aggr[grow * 128 + col] = silu_f(v + bji[col]);
        } else {
          u32 c2 = col - 128;
          float rw = 0.f;
#pragma unroll
          for (int q = 0; q < 6; ++q) rw += ldsRbf[rl * 6 + q] * ldsWr[q * 128 + c2];
          ek[grow * 128 + c2] = f2bf(silu_f(v + bkj[c2]) * rw);
        }
      }
    }
  }
}

// ---------------------------------------------------------------------------
// S4 v5b: r9 structure, launch_bounds (256,2) — the r6/r9 lesson: this body
// needs >=~116 VGPR; requesting >2 waves/EU forces a spill cliff (84 VGPR,
// +1 GB scratch traffic).  2 waves/EU is the proven no-spill config.
__global__ __launch_bounds__(256, 2) void k_bil(
    const char* __restrict__ ek, const char* __restrict__ srec,
    const char* __restrict__ WF, float* __restrict__ aggr) {
  extern __shared__ char lds[];
  char* Xl = lds;                         // [128 rows][256B] swizzled bf16 (32768)
  u16* msg16 = (u16*)lds;                 // [128][128] bf16 overlay (32768)
  float* spT = (float*)(lds + 32768);     // [8][128] f32 (4096)
  int* jil = (int*)(lds + 36864);         // 128
  int* kjl = (int*)(lds + 37376);         // 128
  int* rstart = (int*)(lds + 37888);      // 128
  int* scnt = (int*)(lds + 38400);        // 2   -> total 38408
  const u32 tid = threadIdx.x, lane = tid & 63, wid = tid >> 6;
  const u32 wm = wid >> 1, wn = wid & 1, rb = wm << 6, cb = wn << 6;
  const u32 t0 = blockIdx.x << 7;

  // phase A: coalesced srec read -> indices + spT
  if (tid < 128) {
    const char* rp = srec + (size_t)(t0 + tid) * 32;
    u32x4 a = *(const u32x4*)rp;
    u32 c0 = *(const u32*)(rp + 16);
    u32 c1 = *(const u32*)(rp + 20);
    kjl[tid] = (int)a[0];
    jil[tid] = (int)a[1];
    spT[0 * 128 + tid] = bf2f(a[2] & 0xffffu);
    spT[1 * 128 + tid] = bf2f(a[2] >> 16);
    spT[2 * 128 + tid] = bf2f(a[3] & 0xffffu);
    spT[3 * 128 + tid] = bf2f(a[3] >> 16);
    spT[4 * 128 + tid] = bf2f(c0 & 0xffffu);
    spT[5 * 128 + tid] = bf2f(c0 >> 16);
    spT[6 * 128 + tid] = bf2f(c1 & 0xffffu);
    spT[7 * 128 + tid] = bf2f(c1 >> 16);
  }
  __syncthreads();

  // phase B: X gather (async)
#pragma unroll
  for (int it = 0; it < 8; ++it) {
    u32 q = tid + it * 256, row = q >> 4, c = q & 15;
    gld_lds16(ek + (size_t)kjl[row] * 256 + ((c ^ (row & 7)) << 4), Xl + q * 16);
  }
  // run-detect overlaps the gather latency
  int isS = 0;
  u32 pre = 0;
  if (tid < 128) {
    isS = (tid == 0) || (jil[tid] != jil[tid - 1]);
    u64 mask = __ballot(isS);
    pre = (u32)__popcll(mask & ((1ull << lane) - 1ull));
    if (lane == 0) scnt[wid] = (int)__popcll(mask);
  }
  WAIT_VM0();
  __syncthreads();
  if (tid < 128 && isS) {
    u32 off = (wid == 1) ? (u32)scnt[0] : 0u;
    rstart[pre + off] = (int)tid;
  }

  // phase C: hoist X fragments to registers
  bf16x8 Afr[4][4];
#pragma unroll
  for (int mi = 0; mi < 4; ++mi) {
    u32 row = rb + mi * 16 + (lane & 15);
#pragma unroll
    for (int ks = 0; ks < 4; ++ks)
      Afr[mi][ks] = *(const bf16x8*)(Xl + (row << 8) + ((((u32)(ks * 4) + (lane >> 4)) ^ (row & 7)) << 4));
  }
  __syncthreads();   // all waves hoisted + rstart visible; X region reusable as msg

  // phase D: barrier-free b-loop, W fragments direct from global (L2-hot)
  f32x4 acc[4][4] = {};
  for (int b = 0; b < 8; ++b) {
    const char* wb = WF + (size_t)b * 32768;
    bf16x8 Bf[4][4];
#pragma unroll
    for (int ni = 0; ni < 4; ++ni)
#pragma unroll
      for (int ks = 0; ks < 4; ++ks) Bf[ni][ks] = ldfrag(wb, wn * 4 + ni, ks, lane);
#pragma unroll
    for (int mi = 0; mi < 4; ++mi) {
      f32x4 s4 = *(const f32x4*)(spT + b * 128 + rb + mi * 16 + ((lane >> 4) << 2));
#pragma unroll
      for (int ni = 0; ni < 4; ++ni) {
        f32x4 p = {0.f, 0.f, 0.f, 0.f};
#pragma unroll
        for (int ks = 0; ks < 4; ++ks) p = mfma16(Afr[mi][ks], Bf[ni][ks], p);
        acc[mi][ni] += s4 * p;
      }
    }
  }

  // phase E: spill acc -> bf16 msg (overlay X)
#pragma unroll
  for (int mi = 0; mi < 4; ++mi) {
    u32 rloc = rb + mi * 16 + ((lane >> 4) << 2);
#pragma unroll
    for (int j = 0; j < 4; ++j) {
      u16* drow = msg16 + (size_t)(rloc + j) * 128 + cb + (lane & 15);
#pragma unroll
      for (int ni = 0; ni < 4; ++ni) drow[ni * 16] = f2bf(acc[mi][ni][j]);
    }
  }
  __syncthreads();

  // phase F: one atomic per (run, col), contiguous cols per wave
  const u32 nr = (u32)(scnt[0] + scnt[1]);
  for (u32 task = tid; task < nr * 128; task += 256) {
    u32 run = task >> 7, col = task & 127;
    int ra = rstart[run];
    int rz = (run + 1 < nr) ? rstart[run + 1] : 128;
    float s = 0.f;
    for (int r = ra; r < rz; ++r) s += bf2f(msg16[(size_t)r * 128 + col]);
    unsafeAtomicAdd(&aggr[(size_t)jil[ra] * 128 + col], s);
  }
}

// ---------------------------------------------------------------------------
// S5: fused residual chain (W staged to LDS, overlapped w/ epilogue).
__global__ __launch_bounds__(256, 2) void k_res(
    const float* __restrict__ aggr, const float* __restrict__ m,
    const char* __restrict__ rT,
    const float* __restrict__ rb1, const float* __restrict__ rb2,
    const float* __restrict__ rb3, const float* __restrict__ rb4,
    const float* __restrict__ bo, float* __restrict__ out) {
  extern __shared__ char lds[];
  char* ldsA = lds;
  char* ldsB = lds + 32768;
  const u32 tid = threadIdx.x, lane = tid & 63, wid = tid >> 6;
  const u32 r0 = blockIdx.x << 7;
  const u32 wm = wid >> 1, wn = wid & 1, rbw = wm << 6, cbw = wn << 6;
  const u32 lrow = (lane >> 4) << 2, lcol = lane & 15;

  auto stageB = [&](const char* WT) {
#pragma unroll
    for (int it = 0; it < 8; ++it) {
      u32 q = tid + it * 256, n = q >> 4, c = q & 15;
      gld_lds16(WT + n * 256 + ((c ^ (n & 7)) << 4), ldsB + q * 16);
    }
  };
  auto writeA = [&](u32 row, u32 col, float v) {
    *(u16*)(ldsA + (row << 8) + ((((col >> 3)) ^ (row & 7)) << 4) + (col & 7) * 2) = f2bf(v);
  };
  auto compute = [&](f32x4 (&acc)[4][4]) {
#pragma unroll
    for (int mi = 0; mi < 4; ++mi) {
      u32 row = rbw + mi * 16 + lcol;
      bf16x8 Af[4];
#pragma unroll
      for (int ks = 0; ks < 4; ++ks)
        Af[ks] = *(const bf16x8*)(ldsA + (row << 8) + ((((u32)(ks * 4) + (lane >> 4)) ^ (row & 7)) << 4));
#pragma unroll
      for (int ni = 0; ni < 4; ++ni) {
        u32 n = cbw + ni * 16 + lcol;
#pragma unroll
        for (int ks = 0; ks < 4; ++ks) {
          bf16x8 Bk = *(const bf16x8*)(ldsB + (n << 8) + ((((u32)(ks * 4) + (lane >> 4)) ^ (n & 7)) << 4));
          acc[mi][ni] = mfma16(Af[ks], Bk, acc[mi][ni]);
        }
      }
    }
  };
  auto zero = [&](f32x4 (&acc)[4][4]) {
#pragma unroll
    for (int a = 0; a < 4; ++a)
#pragma unroll
      for (int c = 0; c < 4; ++c) acc[a][c] = (f32x4){0.f, 0.f, 0.f, 0.f};
  };

  f32x4 xr[4][4];
#pragma unroll
  for (int mi = 0; mi < 4; ++mi)
#pragma unroll
    for (int j = 0; j < 4; ++j) {
      const float* src = aggr + (size_t)(r0 + rbw + mi * 16 + lrow + j) * 128 + cbw + lcol;
#pragma unroll
      for (int ni = 0; ni < 4; ++ni) xr[mi][ni][j] = src[ni * 16];
    }
  stageB(rT);
#pragma unroll
  for (int mi = 0; mi < 4; ++mi)
#pragma unroll
    for (int j = 0; j < 4; ++j) {
      u32 row = rbw + mi * 16 + lrow + j;
#pragma unroll
      for (int ni = 0; ni < 4; ++ni) writeA(row, cbw + ni * 16 + lcol, silu_f(xr[mi][ni][j]));
    }
  __syncthreads();

  f32x4 acc[4][4];
  zero(acc); compute(acc);
  __syncthreads();
#pragma unroll
  for (int mi = 0; mi < 4; ++mi)
#pragma unroll
    for (int j = 0; j < 4; ++j) {
      u32 row = rbw + mi * 16 + lrow + j;
#pragma unroll
      for (int ni = 0; ni < 4; ++ni) {
        u32 col = cbw + ni * 16 + lcol;
        writeA(row, col, silu_f(acc[mi][ni][j] + rb1[col]));
      }
    }
  stageB(rT + 32768);
  __syncthreads();

  zero(acc); compute(acc);
  __syncthreads();
#pragma unroll
  for (int mi = 0; mi < 4; ++mi)
#pragma unroll
    for (int j = 0; j < 4; ++j) {
      u32 row = rbw + mi * 16 + lrow + j;
#pragma unroll
      for (int ni = 0; ni < 4; ++ni) {
        u32 col = cbw + ni * 16 + lcol;
        xr[mi][ni][j] += acc[mi][ni][j] + rb2[col];
        writeA(row, col, silu_f(xr[mi][ni][j]));
      }
    }
  stageB(rT + 65536);
  __syncthreads();

  zero(acc); compute(acc);
  __syncthreads();
#pragma unroll
  for (int mi = 0; mi < 4; ++mi)
#pragma unroll
    for (int j = 0; j < 4; ++j) {
      u32 row = rbw + mi * 16 + lrow + j;
#pragma unroll
      for (int ni = 0; ni < 4; ++ni) {
        u32 col = cbw + ni * 16 + lcol;
        writeA(row, col, silu_f(acc[mi][ni][j] + rb3[col]));
      }
    }
  stageB(rT + 98304);
  __syncthreads();

  zero(acc); compute(acc);
  __syncthreads();
#pragma unroll
  for (int mi = 0; mi < 4; ++mi)
#pragma unroll
    for (int j = 0; j < 4; ++j) {
      u32 row = rbw + mi * 16 + lrow + j;
#pragma unroll
      for (int ni = 0; ni < 4; ++ni) {
        u32 col = cbw + ni * 16 + lcol;
        xr[mi][ni][j] += acc[mi][ni][j] + rb4[col];
        writeA(row, col, xr[mi][ni][j]);
      }
    }
  stageB(rT + 131072);
#pragma unroll
  for (int mi = 0; mi < 4; ++mi)
#pragma unroll
    for (int j = 0; j < 4; ++j) {
      const float* src = m + (size_t)(r0 + rbw + mi * 16 + lrow + j) * 128 + cbw + lcol;
#pragma unroll
      for (int ni = 0; ni < 4; ++ni) xr[mi][ni][j] = src[ni * 16];
    }
  __syncthreads();

  zero(acc); compute(acc);
#pragma unroll
  for (int mi = 0; mi < 4; ++mi)
#pragma unroll
    for (int j = 0; j < 4; ++j) {
      size_t grow = r0 + rbw + mi * 16 + lrow + j;
#pragma unroll
      for (int ni = 0; ni < 4; ++ni) {
        u32 col = cbw + ni * 16 + lcol;
        out[grow * 128 + col] = xr[mi][ni][j] + silu_f(acc[mi][ni][j] + bo[col]);
      }
    }
}

// ---------------------------------------------------------------------------
extern "C" void kernel_launch(void* const* d_in, const int* in_sizes, int n_in,
                              void* d_out, int out_size, void* d_ws, size_t ws_size,
                              hipStream_t stream) {
  const float* m = (const float*)d_in[0];
  const float* rbf = (const float*)d_in[1];
  const float* sbf = (const float*)d_in[2];
  const int* trip = (const int*)d_in[4];
  const float* Wrbf = (const float*)d_in[5];
  const float* Wsbf = (const float*)d_in[6];
  const float* bkj = (const float*)d_in[8];
  const float* bji = (const float*)d_in[10];
  const float* r1b1 = (const float*)d_in[13];
  const float* r1b2 = (const float*)d_in[15];
  const float* r2b1 = (const float*)d_in[17];
  const float* r2b2 = (const float*)d_in[19];
  const float* bout = (const float*)d_in[21];

  char* ws = (char*)d_ws;
  char* W2F = ws;                          // 65536 B (frag-major)
  char* WF = ws + 65536;                   // 262144 B (frag-major)
  char* rT = ws + 327680;                  // 163840 B (plain [n][k])
  u16* ek = (u16*)(ws + 524288);           // E*128 bf16 (33.5 MB)
  char* srec = ws + 34078720;              // T*32B sorted records (33.5 MB)
  float* aggr = (float*)(ws + 67633152);   // E*128 f32 (67 MB)
  int* cnt = (int*)(ws + 134742016);       // 131072 int
  int* offsA = (int*)(ws + 135266304);     // 131072 int
  int* blksum = (int*)(ws + 135790592);    // 512 int
  int* blkoff = (int*)(ws + 135792640);    // 512 int
  int* offs_work = (int*)(ws + 135794688); // 131072 int

  hipFuncSetAttribute((const void*)k_mid, hipFuncAttributeMaxDynamicSharedMemorySize, 38912);
  hipFuncSetAttribute((const void*)k_bil, hipFuncAttributeMaxDynamicSharedMemorySize, 38912);
  hipFuncSetAttribute((const void*)k_res, hipFuncAttributeMaxDynamicSharedMemorySize, 65536);

  hipMemsetAsync(cnt, 0, 131072 * sizeof(int), stream);
  k_init<<<5056, 256, 0, stream>>>(
      (const float*)d_in[9], (const float*)d_in[7], (const float*)d_in[11],
      (const float*)d_in[12], (const float*)d_in[14], (const float*)d_in[16],
      (const float*)d_in[18], (const float*)d_in[20], (u16*)ws, trip, cnt);
  k_scanA<<<512, 256, 0, stream>>>(cnt, offsA, blksum);
  k_scanB<<<1, 512, 0, stream>>>(blksum, blkoff);
  k_scanC<<<512, 256, 0, stream>>>(offsA, blkoff, offs_work);
  k_mid<<<3072, 512, 38912, stream>>>(m, rbf, Wrbf, bkj, bji, W2F, aggr, ek,
                                      trip, sbf, Wsbf, offs_work, srec);
  k_bil<<<8192, 256, 38912, stream>>>((const char*)ek, (const char*)srec, WF, aggr);
  k_res<<<1024, 256, 65536, stream>>>(aggr, m, rT, r1b1, r1b2, r2b1, r2b2, bout,
                                      (float*)d_out);
}